// Round 7
// baseline (28370.703 us; speedup 1.0000x reference)
//
#include <hip/hip_runtime.h>
#include <math.h>

// ---------------------------------------------------------------------------
// Persistent LSTM v7 for MI355X — pipelined sc1 h-loads + L2-resident weights.
//   B=128, T=512, IN=64, H=1024, 2 layers, head OUT=1 on last step.
//
// Lessons encoded here:
//  v2: per-WG threadfence (wbl2+inv) = 38us/iter.      -> NO cache maintenance.
//  v3: ATOMIC sc1 h loads (2x8B, serialized) = 57us.   -> raw asm sc1 loads,
//      depth-2 software pipeline, manual vmcnt.
//  v4: per-wave buffer_inv = 65us.                     -> no inv; weights use
//      plain cached loads and stay L2-resident (nothing ever invalidates L2).
//  v5/v6: per-step dispatches re-stream everything from MALL = 47us/step.
//
// Decomposition (v4/v6-proven): 256 WGs = 128 col-groups x 2 batch-groups;
// WG owns 8 h-cols (32 gate rows = 2 B-tiles) x 64 batch rows (4 A-tiles);
// K split over 8 waves; LDS atomicAdd reduction; 1 cell/thread/layer;
// c-state in registers. cg,cg+128 share an XCD (128 % 8 == 0) -> per-XCD
// packed-weight slice 16 x 196KB = 3.1MB < 4MB L2, resident across all iters.
// h coherence: producers write-through (agent atomic stores, 8B); consumers
// read MALL via sc0/sc1/nt loads. Distributed flag barrier (v3/v4-proven).
// ---------------------------------------------------------------------------

#define Hd 1024
#define Bd 128
#define Td 512
#define INd 64
#define NWG 256
#define NTHR 512

typedef _Float16 f16;
typedef _Float16 half8 __attribute__((ext_vector_type(8)));
typedef float f32x4 __attribute__((ext_vector_type(4)));

// ---- raw 16B loads: voff = byte offset (VGPR), base = SGPR pointer ----
#define LDG_SC1(dst, voff, base) \
    asm volatile("global_load_dwordx4 %0, %1, %2 sc0 sc1 nt" \
                 : "=v"(dst) : "v"(voff), "s"(base) : "memory")
#define LDG_CA(dst, voff, base) \
    asm volatile("global_load_dwordx4 %0, %1, %2" \
                 : "=v"(dst) : "v"(voff), "s"(base) : "memory")
#define LDG_CA_OFF(dst, voff, base, OFFSTR) \
    asm volatile("global_load_dwordx4 %0, %1, %2 offset:" OFFSTR \
                 : "=v"(dst) : "v"(voff), "s"(base) : "memory")

// ---- waitcnt tying the loaded regs so MFMAs can't be hoisted above ----
#define WAITV8(NSTR, a0,a1,a2,a3,a4,a5,a6,a7) \
    asm volatile("s_waitcnt vmcnt(" NSTR ")" \
        : "+v"(a0),"+v"(a1),"+v"(a2),"+v"(a3), \
          "+v"(a4),"+v"(a5),"+v"(a6),"+v"(a7) :: "memory")
#define WAITV6(NSTR, a0,a1,a2,a3,a4,a5) \
    asm volatile("s_waitcnt vmcnt(" NSTR ")" \
        : "+v"(a0),"+v"(a1),"+v"(a2),"+v"(a3),"+v"(a4),"+v"(a5) :: "memory")

__device__ __forceinline__ half8 ldcvt8(const float* p) {
    float4 a = *(const float4*)p;
    float4 b = *(const float4*)(p + 4);
    half8 h;
    h[0] = (f16)a.x; h[1] = (f16)a.y; h[2] = (f16)a.z; h[3] = (f16)a.w;
    h[4] = (f16)b.x; h[5] = (f16)b.y; h[6] = (f16)b.z; h[7] = (f16)b.w;
    return h;
}

// ---------------- init ----------------
__global__ __launch_bounds__(512) void init_state(
    const float* __restrict__ bnd, const float* __restrict__ Wb0,
    const float* __restrict__ bb0, const float* __restrict__ Wb1,
    const float* __restrict__ bb1,
    const float* __restrict__ bx0, const float* __restrict__ bh0,
    const float* __restrict__ bx1, const float* __restrict__ bh1,
    float* __restrict__ bi0, float* __restrict__ bi1,
    float* __restrict__ c0g, float* __restrict__ c1g,
    f16* __restrict__ h0buf, f16* __restrict__ h1buf,
    float* __restrict__ gb0, float* __restrict__ gb1,
    unsigned int* __restrict__ flags)
{
    int idx = blockIdx.x * 512 + threadIdx.x;   // [0, B*H)
    int b = idx >> 10;
    int h = idx & 1023;
    float b0v = bnd[b * 2 + 0], b1v = bnd[b * 2 + 1];
    bi0[idx] = b0v * Wb0[h * 2 + 0] + b1v * Wb0[h * 2 + 1] + bb0[h];
    bi1[idx] = b0v * Wb1[h * 2 + 0] + b1v * Wb1[h * 2 + 1] + bb1[h];
    c0g[idx] = 0.f;
    c1g[idx] = 0.f;
    h0buf[idx] = (f16)0.f;  h0buf[idx + Bd * Hd] = (f16)0.f;
    h1buf[idx] = (f16)0.f;  h1buf[idx + Bd * Hd] = (f16)0.f;
    if (idx < 4096) {
        gb0[idx] = bx0[idx] + bh0[idx];
        gb1[idx] = bx1[idx] + bh1[idx];
    }
    if (idx < NWG) flags[idx] = 0u;
}

// ---------------- pack layer-1 weights (v6-proven) ----------------
__global__ __launch_bounds__(512) void pack1(
    const float* __restrict__ Wx1, const float* __restrict__ Uh1,
    f16* __restrict__ W1p)
{
    unsigned i = blockIdx.x * 512 + threadIdx.x;   // 1,048,576 units of 8 f16
    int cg = i >> 13;
    int rem = i & 8191;
    int ch = rem >> 7;
    int u = rem & 127;
    int j = u >> 2, q = u & 3;
    int row = (j >> 3) * Hd + cg * 8 + (j & 7);
    int kb = ch * 32 + q * 8;
    const float* src = (ch < 32) ? (Wx1 + (size_t)row * Hd + kb)
                                 : (Uh1 + (size_t)row * Hd + (kb - 1024));
    half8 v = ldcvt8(src);
    *(half8*)(W1p + (size_t)i * 8) = v;
}

// ---------------- pack layer-0 weights (v6-proven) ----------------
__global__ __launch_bounds__(512) void pack0(
    const float* __restrict__ Uh0, const float* __restrict__ Wx0,
    f16* __restrict__ W0p, f16* __restrict__ Wx0p)
{
    unsigned i = blockIdx.x * 512 + threadIdx.x;
    if (i < 524288u) {
        int cg = i >> 12;
        int rem = i & 4095;
        int ch = rem >> 7;
        int u = rem & 127;
        int j = u >> 2, q = u & 3;
        int row = (j >> 3) * Hd + cg * 8 + (j & 7);
        int kb = ch * 32 + q * 8;
        half8 v = ldcvt8(Uh0 + (size_t)row * Hd + kb);
        *(half8*)(W0p + (size_t)i * 8) = v;
    } else {
        unsigned i2 = i - 524288u;                 // < 32768
        int cg = i2 >> 8;
        int rem = i2 & 255;
        int ch = rem >> 7;
        int u = rem & 127;
        int j = u >> 2, q = u & 3;
        int row = (j >> 3) * Hd + cg * 8 + (j & 7);
        int kb = ch * 32 + q * 8;
        half8 v = ldcvt8(Wx0 + (size_t)row * INd + kb);
        *(half8*)(Wx0p + (size_t)i2 * 8) = v;
    }
}

// ---------------- persistent LSTM ----------------
__global__ __launch_bounds__(NTHR, 2) void lstm_persist(
    const float* __restrict__ x,
    f16* __restrict__ h0b_, f16* __restrict__ h1b_,
    const float* __restrict__ bi0, const float* __restrict__ bi1,
    const f16* __restrict__ W1p, const f16* __restrict__ W0p,
    const f16* __restrict__ Wx0p,
    const float* __restrict__ gb0a, const float* __restrict__ gb1a,
    const float* __restrict__ fcW, const float* __restrict__ fcb,
    float* __restrict__ out, unsigned int* __restrict__ flags)
{
    const int tid  = threadIdx.x;
    const int w    = tid >> 6;        // wave 0..7
    const int lane = tid & 63;
    const int n    = lane & 15;
    const int q    = lane >> 4;
    const int wg   = blockIdx.x;
    const int cg   = wg & 127;        // col group (cg and cg+? share XCD: wg%8)
    const int bg   = wg >> 7;         // batch group
    const int Rb   = bg * 64;
    const size_t S2 = (size_t)Bd * Hd;

    __shared__ float ACC[2][8][256];   // 16 KB
    __shared__ f16 HST[2][64][8];
    __shared__ float red[8];

    // packed-weight slice bases (wave-uniform)
    const char* W1cg = (const char*)W1p + (size_t)cg * 131072;
    const char* W0cg = (const char*)W0p + (size_t)cg * 65536;

    // per-lane byte offsets (constant across iterations)
    unsigned vA[4];
    #pragma unroll
    for (int a = 0; a < 4; ++a)
        vA[a] = (unsigned)((Rb + a * 16 + n) * 2048 + (w & 3) * 512 + q * 16);
    const unsigned vB = (unsigned)(w * 16384 + n * 64 + q * 16);

    // per-thread cell state: cell (row=Rb+tid>>3, col=cg*8+tid&7)
    const int crow = tid >> 3, ccol = tid & 7;
    const int gR = Rb + crow, gC = cg * 8 + ccol;
    float gb0[4], gb1[4];
    #pragma unroll
    for (int g = 0; g < 4; ++g) {
        gb0[g] = gb0a[g * Hd + gC];
        gb1[g] = gb1a[g * Hd + gC];
    }
    const float ba0 = bi0[(size_t)gR * Hd + gC];
    const float ba1 = bi1[(size_t)gR * Hd + gC];
    float c0s = 0.f, c1s = 0.f;
    const int ca = crow >> 4, crr = crow & 15;

    for (int s = -1; s <= 511; ++s) {
        const bool doL0 = (s < 511), doL1 = (s >= 0);
        const f16* h0r = h0b_ + (size_t)(s & 1) * S2;         // h0(s)
        f16*       h0w = h0b_ + (size_t)((s + 1) & 1) * S2;   // h0(s+1)
        const f16* h1r = h1b_ + (size_t)((s - 1) & 1) * S2;   // h1(s-1)
        f16*       h1w = h1b_ + (size_t)(s & 1) * S2;         // h1(s)

        // zero ACC
        {
            float* az = &ACC[0][0][0];
            #pragma unroll
            for (int i = 0; i < 8; ++i) az[tid + i * 512] = 0.f;
        }

        f32x4 aL1[4][2], aL0[4][2];
        #pragma unroll
        for (int a = 0; a < 4; ++a)
            #pragma unroll
            for (int bt = 0; bt < 2; ++bt) {
                aL1[a][bt] = (f32x4){0.f, 0.f, 0.f, 0.f};
                aL0[a][bt] = (f32x4){0.f, 0.f, 0.f, 0.f};
            }

        if (w < 4) {
            // ---- low waves: A = h0(s) (sc1), B = W1p & W0p chunks w*8+kk ----
            const void* hb = (const void*)h0r;
            half8 A[2][4], B1v[2][2], B0v[2][2];
            #define ISSUE_LOW(sl, kk) do {                                   \
                LDG_SC1(A[sl][0], vA[0] + (kk) * 64, hb);                    \
                LDG_SC1(A[sl][1], vA[1] + (kk) * 64, hb);                    \
                LDG_SC1(A[sl][2], vA[2] + (kk) * 64, hb);                    \
                LDG_SC1(A[sl][3], vA[3] + (kk) * 64, hb);                    \
                LDG_CA_OFF(B1v[sl][0], vB + (kk) * 2048, W1cg, "0");         \
                LDG_CA_OFF(B1v[sl][1], vB + (kk) * 2048, W1cg, "1024");      \
                LDG_CA_OFF(B0v[sl][0], vB + (kk) * 2048, W0cg, "0");         \
                LDG_CA_OFF(B0v[sl][1], vB + (kk) * 2048, W0cg, "1024");      \
            } while (0)
            ISSUE_LOW(0, 0);
            #pragma unroll
            for (int kk = 0; kk < 8; ++kk) {
                const int cs = kk & 1;
                if (kk < 7) {
                    ISSUE_LOW(cs ^ 1, kk + 1);
                    WAITV8("8", A[cs][0], A[cs][1], A[cs][2], A[cs][3],
                                B1v[cs][0], B1v[cs][1], B0v[cs][0], B0v[cs][1]);
                } else {
                    WAITV8("0", A[cs][0], A[cs][1], A[cs][2], A[cs][3],
                                B1v[cs][0], B1v[cs][1], B0v[cs][0], B0v[cs][1]);
                }
                if (doL1) {
                    #pragma unroll
                    for (int a = 0; a < 4; ++a) {
                        aL1[a][0] = __builtin_amdgcn_mfma_f32_16x16x32_f16(
                            A[cs][a], B1v[cs][0], aL1[a][0], 0, 0, 0);
                        aL1[a][1] = __builtin_amdgcn_mfma_f32_16x16x32_f16(
                            A[cs][a], B1v[cs][1], aL1[a][1], 0, 0, 0);
                    }
                }
                if (doL0) {
                    #pragma unroll
                    for (int a = 0; a < 4; ++a) {
                        aL0[a][0] = __builtin_amdgcn_mfma_f32_16x16x32_f16(
                            A[cs][a], B0v[cs][0], aL0[a][0], 0, 0, 0);
                        aL0[a][1] = __builtin_amdgcn_mfma_f32_16x16x32_f16(
                            A[cs][a], B0v[cs][1], aL0[a][1], 0, 0, 0);
                    }
                }
            }
            #undef ISSUE_LOW
        } else if (doL1) {
            // ---- high waves: A = h1(s-1) (sc1), B = W1p chunks w*8+kk ----
            const void* hb = (const void*)h1r;
            half8 A[2][4], B1v[2][2];
            #define ISSUE_HIGH(sl, kk) do {                                  \
                LDG_SC1(A[sl][0], vA[0] + (kk) * 64, hb);                    \
                LDG_SC1(A[sl][1], vA[1] + (kk) * 64, hb);                    \
                LDG_SC1(A[sl][2], vA[2] + (kk) * 64, hb);                    \
                LDG_SC1(A[sl][3], vA[3] + (kk) * 64, hb);                    \
                LDG_CA_OFF(B1v[sl][0], vB + (kk) * 2048, W1cg, "0");         \
                LDG_CA_OFF(B1v[sl][1], vB + (kk) * 2048, W1cg, "1024");      \
            } while (0)
            ISSUE_HIGH(0, 0);
            #pragma unroll
            for (int kk = 0; kk < 8; ++kk) {
                const int cs = kk & 1;
                if (kk < 7) {
                    ISSUE_HIGH(cs ^ 1, kk + 1);
                    WAITV6("6", A[cs][0], A[cs][1], A[cs][2], A[cs][3],
                                B1v[cs][0], B1v[cs][1]);
                } else {
                    WAITV6("0", A[cs][0], A[cs][1], A[cs][2], A[cs][3],
                                B1v[cs][0], B1v[cs][1]);
                }
                #pragma unroll
                for (int a = 0; a < 4; ++a) {
                    aL1[a][0] = __builtin_amdgcn_mfma_f32_16x16x32_f16(
                        A[cs][a], B1v[cs][0], aL1[a][0], 0, 0, 0);
                    aL1[a][1] = __builtin_amdgcn_mfma_f32_16x16x32_f16(
                        A[cs][a], B1v[cs][1], aL1[a][1], 0, 0, 0);
                }
            }
            #undef ISSUE_HIGH
        }

        // ---- x-projection (waves 6,7): plain code — own vmcnt is 0 here ----
        if (w >= 6 && doL0) {
            const f16* cbx = Wx0p + (size_t)cg * 2048 + (size_t)(w - 6) * 1024;
            half8 XB0 = *(const half8*)(cbx + n * 32 + q * 8);
            half8 XB1 = *(const half8*)(cbx + (16 + n) * 32 + q * 8);
            const int ko = (w - 6) * 32 + q * 8;
            #pragma unroll
            for (int a = 0; a < 4; ++a) {
                half8 Af = ldcvt8(x + ((size_t)(Rb + a * 16 + n) * Td + (s + 1)) * INd + ko);
                aL0[a][0] = __builtin_amdgcn_mfma_f32_16x16x32_f16(Af, XB0, aL0[a][0], 0, 0, 0);
                aL0[a][1] = __builtin_amdgcn_mfma_f32_16x16x32_f16(Af, XB1, aL0[a][1], 0, 0, 0);
            }
        }

        __syncthreads();   // ACC zero + all partials ready

        if (doL1) {
            #pragma unroll
            for (int a = 0; a < 4; ++a)
                #pragma unroll
                for (int bt = 0; bt < 2; ++bt)
                    #pragma unroll
                    for (int r = 0; r < 4; ++r)
                        atomicAdd(&ACC[1][a * 2 + bt][(q * 4 + r) * 16 + n],
                                  aL1[a][bt][r]);
        }
        if (doL0 && (w < 4 || w >= 6)) {
            #pragma unroll
            for (int a = 0; a < 4; ++a)
                #pragma unroll
                for (int bt = 0; bt < 2; ++bt)
                    #pragma unroll
                    for (int r = 0; r < 4; ++r)
                        atomicAdd(&ACC[0][a * 2 + bt][(q * 4 + r) * 16 + n],
                                  aL0[a][bt][r]);
        }
        __syncthreads();

        // ---- cell updates -> stage h in LDS ----
        if (doL0) {
            float ip = ACC[0][ca * 2 + 0][crr * 16 + ccol]     + gb0[0];
            float fp = ACC[0][ca * 2 + 0][crr * 16 + 8 + ccol] + gb0[1] + ba0;
            float op = ACC[0][ca * 2 + 1][crr * 16 + ccol]     + gb0[2];
            float gp = ACC[0][ca * 2 + 1][crr * 16 + 8 + ccol] + gb0[3];
            float I = 1.f / (1.f + expf(-ip));
            float F = 1.f / (1.f + expf(-fp));
            float O = 1.f / (1.f + expf(-op));
            float G = tanhf(gp);
            c0s = F * c0s + I * G;
            HST[0][crow][ccol] = (f16)(O * tanhf(c0s));
        }
        if (doL1) {
            float ip = ACC[1][ca * 2 + 0][crr * 16 + ccol]     + gb1[0];
            float fp = ACC[1][ca * 2 + 0][crr * 16 + 8 + ccol] + gb1[1] + ba1;
            float op = ACC[1][ca * 2 + 1][crr * 16 + ccol]     + gb1[2];
            float gp = ACC[1][ca * 2 + 1][crr * 16 + 8 + ccol] + gb1[3];
            float I = 1.f / (1.f + expf(-ip));
            float F = 1.f / (1.f + expf(-fp));
            float O = 1.f / (1.f + expf(-op));
            float G = tanhf(gp);
            c1s = F * c1s + I * G;
            HST[1][crow][ccol] = (f16)(O * tanhf(c1s));
        }
        __syncthreads();

        // ---- write-through h stores: 8 B agent-scope ----
        if (tid < 256) {
            int L = tid >> 7, idx = tid & 127, row = idx >> 1, hh = idx & 1;
            bool go = L ? doL1 : doL0;
            if (go) {
                unsigned long long v =
                    *(const unsigned long long*)&HST[L][row][hh * 4];
                f16* dst = (L ? h1w : h0w) + (size_t)(Rb + row) * Hd + cg * 8 + hh * 4;
                __hip_atomic_store((unsigned long long*)dst, v,
                                   __ATOMIC_RELAXED, __HIP_MEMORY_SCOPE_AGENT);
            }
        }
        asm volatile("s_waitcnt vmcnt(0)" ::: "memory");
        __syncthreads();

        // ---- distributed flag barrier ----
        const unsigned target = (unsigned)(s + 2);
        if (tid == 0)
            __hip_atomic_store(&flags[wg], target,
                               __ATOMIC_RELAXED, __HIP_MEMORY_SCOPE_AGENT);
        if (w == 0) {
            while (true) {
                unsigned f0 = __hip_atomic_load(&flags[lane],
                                 __ATOMIC_RELAXED, __HIP_MEMORY_SCOPE_AGENT);
                unsigned f1 = __hip_atomic_load(&flags[64 + lane],
                                 __ATOMIC_RELAXED, __HIP_MEMORY_SCOPE_AGENT);
                unsigned f2 = __hip_atomic_load(&flags[128 + lane],
                                 __ATOMIC_RELAXED, __HIP_MEMORY_SCOPE_AGENT);
                unsigned f3 = __hip_atomic_load(&flags[192 + lane],
                                 __ATOMIC_RELAXED, __HIP_MEMORY_SCOPE_AGENT);
                bool ok = (f0 >= target) && (f1 >= target) &&
                          (f2 >= target) && (f3 >= target);
                if (__all(ok)) break;
                __builtin_amdgcn_s_sleep(2);
            }
        }
        asm volatile("" ::: "memory");
        __syncthreads();
    }

    // ---- fc head: out[b] = fcW . h1(511)[b] + fcb (slot 1; MALL reads) ----
    if (wg < Bd) {
        float partial = 0.f;
        if (tid < 256) {
            const f16* hrow = h1b_ + S2 + (size_t)wg * Hd + tid * 4;
            union { unsigned long long u; f16 h[4]; } v;
            v.u = __hip_atomic_load((const unsigned long long*)hrow,
                                    __ATOMIC_RELAXED, __HIP_MEMORY_SCOPE_AGENT);
            const float* fw = fcW + tid * 4;
            partial = (float)v.h[0] * fw[0] + (float)v.h[1] * fw[1]
                    + (float)v.h[2] * fw[2] + (float)v.h[3] * fw[3];
        }
        #pragma unroll
        for (int off = 32; off > 0; off >>= 1) partial += __shfl_down(partial, off);
        if (lane == 0) red[w] = partial;
        __syncthreads();
        if (tid == 0) {
            float t = 0.f;
            #pragma unroll
            for (int i = 0; i < 8; ++i) t += red[i];
            out[wg] = t + fcb[0];
        }
    }
}

// ---------------- fallback: v6 per-step packed kernel ----------------
__global__ __launch_bounds__(512, 4) void step_packed(
    int s,
    const float* __restrict__ x,
    f16* __restrict__ h0buf, f16* __restrict__ h1buf,
    float* __restrict__ c0g, float* __restrict__ c1g,
    const float* __restrict__ bi0, const float* __restrict__ bi1,
    const f16* __restrict__ W1p, const f16* __restrict__ W0p,
    const f16* __restrict__ Wx0p,
    const float* __restrict__ gb0, const float* __restrict__ gb1)
{
    const int bid = blockIdx.x;
    const bool isL1 = (bid < 256);
    if (isL1 && s < 0) return;
    if (!isL1 && s >= 511) return;

    const int tid  = threadIdx.x;
    const int w    = tid >> 6;
    const int lane = tid & 63;
    const int n    = lane & 15;
    const int q    = lane >> 4;
    const int id2  = isL1 ? bid : bid - 256;
    const int cg   = id2 & 127;
    const int bg   = id2 >> 7;
    const int Rb   = bg * 64;
    const size_t S2 = (size_t)Bd * Hd;

    const f16* h0r = h0buf + (size_t)(s & 1) * S2;
    const f16* h1r = h1buf + (size_t)((s - 1) & 1) * S2;
    f16* h1w = h1buf + (size_t)(s & 1) * S2;
    f16* h0w = h0buf + (size_t)((s + 1) & 1) * S2;

    __shared__ float ACC[8][256];
    __shared__ f16 HST[64][8];

    {
        float* az = &ACC[0][0];
        #pragma unroll
        for (int i = 0; i < 4; ++i) az[tid + i * 512] = 0.f;
    }
    __syncthreads();

    f32x4 acc[4][2];
    #pragma unroll
    for (int a = 0; a < 4; ++a) {
        acc[a][0] = (f32x4){0.f, 0.f, 0.f, 0.f};
        acc[a][1] = (f32x4){0.f, 0.f, 0.f, 0.f};
    }

    bool contrib = false;
    if (isL1) {
        const f16* hsrc = (w < 4) ? h0r : h1r;
        const f16* wbase = W1p + (size_t)cg * 65536;
        const int akb = (w & 3) * 256;
        #pragma unroll
        for (int kk = 0; kk < 8; ++kk) {
            const int ako = akb + kk * 32 + q * 8;
            const f16* cb = wbase + (size_t)(w * 8 + kk) * 1024;
            half8 Af[4];
            #pragma unroll
            for (int a = 0; a < 4; ++a)
                Af[a] = *(const half8*)(hsrc + (size_t)(Rb + a * 16 + n) * Hd + ako);
            half8 B0 = *(const half8*)(cb + n * 32 + q * 8);
            half8 B1 = *(const half8*)(cb + (16 + n) * 32 + q * 8);
            #pragma unroll
            for (int a = 0; a < 4; ++a) {
                acc[a][0] = __builtin_amdgcn_mfma_f32_16x16x32_f16(Af[a], B0, acc[a][0], 0, 0, 0);
                acc[a][1] = __builtin_amdgcn_mfma_f32_16x16x32_f16(Af[a], B1, acc[a][1], 0, 0, 0);
            }
        }
        contrib = true;
    } else {
        if (w < 4) {
            const f16* wbase = W0p + (size_t)cg * 32768;
            const int akb = w * 256;
            #pragma unroll
            for (int kk = 0; kk < 8; ++kk) {
                const int ako = akb + kk * 32 + q * 8;
                const f16* cb = wbase + (size_t)(w * 8 + kk) * 1024;
                half8 Af[4];
                #pragma unroll
                for (int a = 0; a < 4; ++a)
                    Af[a] = *(const half8*)(h0r + (size_t)(Rb + a * 16 + n) * Hd + ako);
                half8 B0 = *(const half8*)(cb + n * 32 + q * 8);
                half8 B1 = *(const half8*)(cb + (16 + n) * 32 + q * 8);
                #pragma unroll
                for (int a = 0; a < 4; ++a) {
                    acc[a][0] = __builtin_amdgcn_mfma_f32_16x16x32_f16(Af[a], B0, acc[a][0], 0, 0, 0);
                    acc[a][1] = __builtin_amdgcn_mfma_f32_16x16x32_f16(Af[a], B1, acc[a][1], 0, 0, 0);
                }
            }
            contrib = true;
        } else if (w >= 6) {
            const f16* cb = Wx0p + (size_t)cg * 2048 + (size_t)(w - 6) * 1024;
            const int ko = (w - 6) * 32 + q * 8;
            half8 B0 = *(const half8*)(cb + n * 32 + q * 8);
            half8 B1 = *(const half8*)(cb + (16 + n) * 32 + q * 8);
            #pragma unroll
            for (int a = 0; a < 4; ++a) {
                half8 Af = ldcvt8(x + ((size_t)(Rb + a * 16 + n) * Td + (s + 1)) * INd + ko);
                acc[a][0] = __builtin_amdgcn_mfma_f32_16x16x32_f16(Af, B0, acc[a][0], 0, 0, 0);
                acc[a][1] = __builtin_amdgcn_mfma_f32_16x16x32_f16(Af, B1, acc[a][1], 0, 0, 0);
            }
            contrib = true;
        }
    }

    if (contrib) {
        #pragma unroll
        for (int a = 0; a < 4; ++a)
            #pragma unroll
            for (int bt = 0; bt < 2; ++bt)
                #pragma unroll
                for (int r = 0; r < 4; ++r)
                    atomicAdd(&ACC[a * 2 + bt][(q * 4 + r) * 16 + n], acc[a][bt][r]);
    }
    __syncthreads();

    {
        const int crow = tid >> 3, ccol = tid & 7;
        const int gR = Rb + crow, gC = cg * 8 + ccol;
        const int ca = crow >> 4, crr = crow & 15;
        const float* gb = isL1 ? gb1 : gb0;
        const float* bi = isL1 ? bi1 : bi0;
        float* cst = isL1 ? c1g : c0g;

        float ip = ACC[ca * 2 + 0][crr * 16 + ccol]     + gb[0 * Hd + gC];
        float fp = ACC[ca * 2 + 0][crr * 16 + 8 + ccol] + gb[1 * Hd + gC]
                 + bi[(size_t)gR * Hd + gC];
        float op = ACC[ca * 2 + 1][crr * 16 + ccol]     + gb[2 * Hd + gC];
        float gp = ACC[ca * 2 + 1][crr * 16 + 8 + ccol] + gb[3 * Hd + gC];
        float I = 1.f / (1.f + expf(-ip));
        float F = 1.f / (1.f + expf(-fp));
        float O = 1.f / (1.f + expf(-op));
        float G = tanhf(gp);
        float c = F * cst[(size_t)gR * Hd + gC] + I * G;
        cst[(size_t)gR * Hd + gC] = c;
        HST[crow][ccol] = (f16)(O * tanhf(c));
    }
    __syncthreads();

    if (tid < 128) {
        int row = tid >> 1, hh = tid & 1;
        unsigned long long v = *(const unsigned long long*)&HST[row][hh * 4];
        f16* dst = (isL1 ? h1w : h0w) + (size_t)(Rb + row) * Hd + cg * 8 + hh * 4;
        *(unsigned long long*)dst = v;
    }
}

__global__ __launch_bounds__(256) void fc_kernel(
    const f16* __restrict__ h1, const float* __restrict__ fcW,
    const float* __restrict__ fcb, float* __restrict__ out)
{
    int b = blockIdx.x;
    int tid = threadIdx.x;
    const f16* hrow = h1 + (size_t)b * Hd + tid * 4;
    const float* fw = fcW + tid * 4;
    float sum = (float)hrow[0] * fw[0] + (float)hrow[1] * fw[1]
              + (float)hrow[2] * fw[2] + (float)hrow[3] * fw[3];
    #pragma unroll
    for (int off = 32; off > 0; off >>= 1) sum += __shfl_down(sum, off, 64);
    __shared__ float ls[4];
    if ((tid & 63) == 0) ls[tid >> 6] = sum;
    __syncthreads();
    if (tid == 0) out[b] = ls[0] + ls[1] + ls[2] + ls[3] + fcb[0];
}

// ---------------------------------------------------------------------------
extern "C" void kernel_launch(void* const* d_in, const int* in_sizes, int n_in,
                              void* d_out, int out_size, void* d_ws, size_t ws_size,
                              hipStream_t stream) {
    const float* x        = (const float*)d_in[0];
    const float* boundary = (const float*)d_in[1];
    const float* Wx0      = (const float*)d_in[2];
    const float* bx0      = (const float*)d_in[3];
    const float* Uh0      = (const float*)d_in[4];
    const float* bh0      = (const float*)d_in[5];
    const float* Wb0      = (const float*)d_in[6];
    const float* bb0      = (const float*)d_in[7];
    const float* Wx1      = (const float*)d_in[8];
    const float* bx1      = (const float*)d_in[9];
    const float* Uh1      = (const float*)d_in[10];
    const float* bh1      = (const float*)d_in[11];
    const float* Wb1      = (const float*)d_in[12];
    const float* bb1      = (const float*)d_in[13];
    const float* fcW      = (const float*)d_in[14];
    const float* fcb      = (const float*)d_in[15];
    float* out = (float*)d_out;

    char* ws = (char*)d_ws;
    // layout (bytes)
    f16*   W1p   = (f16*)(ws);                    // 16 MB
    f16*   W0p   = (f16*)(ws + 16777216);         //  8 MB
    f16*   Wx0p  = (f16*)(ws + 25165824);         //  0.5 MB
    f16*   h0buf = (f16*)(ws + 25690112);         //  512 KB (2 slots)
    f16*   h1buf = (f16*)(ws + 26214400);         //  512 KB
    float* c0g   = (float*)(ws + 26738688);       //  512 KB (fallback only)
    float* c1g   = (float*)(ws + 27262976);       //  512 KB
    float* bi0   = (float*)(ws + 27787264);       //  512 KB
    float* bi1   = (float*)(ws + 28311552);       //  512 KB
    float* gb0   = (float*)(ws + 28835840);       //   16 KB
    float* gb1   = (float*)(ws + 28852224);       //   16 KB
    unsigned int* flags = (unsigned int*)(ws + 28868608);  // 1 KB
    const size_t WS_NEEDED = 28869632;

    init_state<<<256, 512, 0, stream>>>(boundary, Wb0, bb0, Wb1, bb1,
                                        bx0, bh0, bx1, bh1,
                                        bi0, bi1, c0g, c1g, h0buf, h1buf,
                                        gb0, gb1, flags);
    pack1<<<2048, 512, 0, stream>>>(Wx1, Uh1, W1p);
    pack0<<<1088, 512, 0, stream>>>(Uh0, Wx0, W0p, Wx0p);

    if (ws_size >= WS_NEEDED) {
        void* args[] = {
            (void*)&x, (void*)&h0buf, (void*)&h1buf, (void*)&bi0, (void*)&bi1,
            (void*)&W1p, (void*)&W0p, (void*)&Wx0p,
            (void*)&gb0, (void*)&gb1,
            (void*)&fcW, (void*)&fcb, (void*)&out, (void*)&flags
        };
        hipLaunchCooperativeKernel((void*)lstm_persist, dim3(NWG), dim3(NTHR),
                                   args, 0, stream);
    } else {
        for (int s = -1; s <= 511; ++s)
            step_packed<<<512, 512, 0, stream>>>(s, x, h0buf, h1buf, c0g, c1g,
                                                 bi0, bi1, W1p, W0p, Wx0p,
                                                 gb0, gb1);
        fc_kernel<<<Bd, 256, 0, stream>>>(h1buf + (size_t)Bd * Hd, fcW, fcb, out);
    }
}